// Round 3
// baseline (609.525 us; speedup 1.0000x reference)
//
#include <hip/hip_runtime.h>

typedef __attribute__((ext_vector_type(8))) short bh8;
typedef __attribute__((ext_vector_type(4))) float f4;

__device__ __forceinline__ unsigned short f2bf(float x) {
  unsigned int u = __float_as_uint(x);
  u += 0x7fffu + ((u >> 16) & 1u);
  return (unsigned short)(u >> 16);
}
__device__ __forceinline__ float bf2f(short x) {
  return __uint_as_float(((unsigned int)(unsigned short)x) << 16);
}
__device__ __forceinline__ void gl_lds16(const short* g, short* l) {
  __builtin_amdgcn_global_load_lds(
      (const __attribute__((address_space(1))) unsigned int*)g,
      (__attribute__((address_space(3))) unsigned int*)l, 16, 0, 0);
}

// ---------------- RoPE table ----------------
__global__ __launch_bounds__(256)
void rope_table(float* __restrict__ ct, float* __restrict__ st) {
  const int idx = blockIdx.x * 256 + threadIdx.x;   // 65536 = 2048*32
  const int s = idx >> 5, j = idx & 31;
  const float invf = expf(-0.28782313662425574f * (float)j);  // 10000^(-j/32)
  const float f = (float)s * invf;
  ct[idx] = cosf(f);
  st[idx] = sinf(f);
}

// ---------------- bias concat for fused QKV ----------------
__global__ __launch_bounds__(256)
void concat_bias(const float* __restrict__ bq, const float* __restrict__ bk,
                 const float* __restrict__ bv, float* __restrict__ bqkv) {
  const int i = blockIdx.x * 256 + threadIdx.x;  // 3072
  bqkv[i] = (i < 1024) ? bq[i] : ((i < 2048) ? bk[i - 1024] : bv[i - 2048]);
}

// ---------------- all weights fp32 -> bf16 (QKV concatenated) ----------------
__global__ __launch_bounds__(256)
void w2bf_all(const float* __restrict__ Wq, const float* __restrict__ Wk,
              const float* __restrict__ Wv, const float* __restrict__ Wo,
              const float* __restrict__ W1, const float* __restrict__ W2,
              short* __restrict__ wqkvb, short* __restrict__ wob,
              short* __restrict__ w1b, short* __restrict__ w2b) {
  const int which = blockIdx.y;
  const float* src; short* dst; int n;
  switch (which) {
    case 0: src = Wq; dst = wqkvb;                 n = 1 << 20; break;
    case 1: src = Wk; dst = wqkvb + (1 << 20);     n = 1 << 20; break;
    case 2: src = Wv; dst = wqkvb + (2 << 20);     n = 1 << 20; break;
    case 3: src = Wo; dst = wob;                   n = 1 << 20; break;
    case 4: src = W1; dst = w1b;                   n = 1 << 22; break;
    default: src = W2; dst = w2b;                  n = 1 << 22; break;
  }
  const int i = (blockIdx.x * 256 + threadIdx.x) * 4;
  if (i >= n) return;
  f4 v = *(const f4*)(src + i);
#pragma unroll
  for (int j = 0; j < 4; ++j) dst[i + j] = (short)f2bf(v[j]);
}

// ---------------- LayerNorm (row=1024) ----------------
__global__ __launch_bounds__(256)
void layernorm_bf(const float* __restrict__ x, const float* __restrict__ g,
                  const float* __restrict__ be, short* __restrict__ out) {
  __shared__ float sb[4];
  const int row = blockIdx.x, t = threadIdx.x;
  const float* xr = x + (size_t)row * 1024;
  f4 v = *(const f4*)(xr + t * 4);
  float s = v[0] + v[1] + v[2] + v[3];
#pragma unroll
  for (int mk = 1; mk < 64; mk <<= 1) s += __shfl_xor(s, mk, 64);
  if ((t & 63) == 0) sb[t >> 6] = s;
  __syncthreads();
  const float mean = (sb[0] + sb[1] + sb[2] + sb[3]) * (1.0f / 1024.0f);
  __syncthreads();
  f4 d;
#pragma unroll
  for (int i = 0; i < 4; ++i) d[i] = v[i] - mean;
  float s2 = d[0] * d[0] + d[1] * d[1] + d[2] * d[2] + d[3] * d[3];
#pragma unroll
  for (int mk = 1; mk < 64; mk <<= 1) s2 += __shfl_xor(s2, mk, 64);
  if ((t & 63) == 0) sb[t >> 6] = s2;
  __syncthreads();
  const float var = (sb[0] + sb[1] + sb[2] + sb[3]) * (1.0f / 1024.0f);
  const float rstd = rsqrtf(var + 1e-5f);
  const f4 gg = *(const f4*)(g + t * 4);
  const f4 bb = *(const f4*)(be + t * 4);
#pragma unroll
  for (int i = 0; i < 4; ++i)
    out[(size_t)row * 1024 + t * 4 + i] = (short)f2bf(d[i] * rstd * gg[i] + bb[i]);
}

// ---------------- in-place RoPE on q|k inside qkv [8192,3072] ----------------
__global__ __launch_bounds__(256)
void rope_apply(short* __restrict__ qkv, const float* __restrict__ ct,
                const float* __restrict__ st) {
  const int off = blockIdx.y ? 1024 : 0;
  const int gid = blockIdx.x * 256 + threadIdx.x;  // 8192*128
  const int row = gid >> 7, chn = gid & 127;
  const int srow = row & 2047;
  const int col = chn * 8;
  const int j0 = (col & 63) >> 1;
  short* p = qkv + (size_t)row * 3072 + off + col;
  bh8 vv = *(const bh8*)p;
  bh8 r;
#pragma unroll
  for (int pp = 0; pp < 4; ++pp) {
    const float e = bf2f(vv[2 * pp]), od = bf2f(vv[2 * pp + 1]);
    const float c = ct[srow * 32 + j0 + pp], sn = st[srow * 32 + j0 + pp];
    r[2 * pp]     = (short)f2bf(e * c - od * sn);
    r[2 * pp + 1] = (short)f2bf(e * sn + od * c);
  }
  *(bh8*)p = r;
}

// ---------------- V transpose: qkv v-section -> vt[b,h,d,s] ----------------
__global__ __launch_bounds__(256)
void v_transpose(const short* __restrict__ qkv, short* __restrict__ vt) {
  __shared__ short tile[64][72];
  const int st = blockIdx.x, bh = blockIdx.y;
  const int b = bh >> 4, hh = bh & 15;
  const int t = threadIdx.x;
  const int r = t >> 3, c = (t & 7) * 8;
#pragma unroll
  for (int p = 0; p < 2; ++p) {
    const int s = st * 64 + p * 32 + r;
    bh8 vv = *(const bh8*)(qkv + ((size_t)b * 2048 + s) * 3072 + 2048 + hh * 64 + c);
    *(bh8*)(&tile[p * 32 + r][c]) = vv;
  }
  __syncthreads();
#pragma unroll
  for (int p = 0; p < 2; ++p) {
    const int d = p * 32 + r;
    bh8 ov;
#pragma unroll
    for (int i = 0; i < 8; ++i) ov[i] = tile[c + i][d];
    *(bh8*)(vt + ((size_t)bh * 64 + d) * 2048 + st * 64 + c) = ov;
  }
}

// ---------------- bf16 B^T GEMM (m97 structure): C = A[M,K]*Bw[N,K]^T + bias (+res)(+relu) ----------------
template <int RELU, int RES, int OBF16>
__global__ __launch_bounds__(256)
void gemm_bt(const short* __restrict__ A, const short* __restrict__ Bw,
             const float* __restrict__ bias, const float* __restrict__ res,
             short* __restrict__ Cb, float* __restrict__ Cf,
             int M, int N, int K) {
  __shared__ short As[128 * 32];
  __shared__ short Bs[128 * 32];
  const int t = threadIdx.x;
  const int lane = t & 63;
  const int w = t >> 6, wr = w >> 1, wc = w & 1;
  const int bm = blockIdx.x, bn = blockIdx.y;
  const int srow = lane >> 2;          // 0..15
  const int scol = (lane & 3) * 8;     // shorts
  f4 acc[4][4] = {};
  const short* Abase = A + (size_t)(bm * 128) * K;
  const short* Bbase = Bw + (size_t)(bn * 128) * K;
  for (int kt = 0; kt < K; kt += 32) {
#pragma unroll
    for (int i = 0; i < 2; ++i) {
      const int r = w * 32 + i * 16 + srow;
      gl_lds16(Abase + (size_t)r * K + kt + scol, &As[(w * 32 + i * 16) * 32]);
      gl_lds16(Bbase + (size_t)r * K + kt + scol, &Bs[(w * 32 + i * 16) * 32]);
    }
    __syncthreads();
    bh8 af[4], bf[4];
#pragma unroll
    for (int m = 0; m < 4; ++m)
      af[m] = *(const bh8*)(&As[(wr * 64 + m * 16 + (lane & 15)) * 32 + (lane >> 4) * 8]);
#pragma unroll
    for (int n = 0; n < 4; ++n)
      bf[n] = *(const bh8*)(&Bs[(wc * 64 + n * 16 + (lane & 15)) * 32 + (lane >> 4) * 8]);
#pragma unroll
    for (int m = 0; m < 4; ++m)
#pragma unroll
      for (int n = 0; n < 4; ++n)
        acc[m][n] = __builtin_amdgcn_mfma_f32_16x16x32_bf16(af[m], bf[n], acc[m][n], 0, 0, 0);
    __syncthreads();
  }
  const int rbase = bm * 128 + wr * 64 + ((lane >> 4) << 2);
  const int cbase = bn * 128 + wc * 64 + (lane & 15);
#pragma unroll
  for (int m = 0; m < 4; ++m) {
#pragma unroll
    for (int n = 0; n < 4; ++n) {
#pragma unroll
      for (int j = 0; j < 4; ++j) {
        const int r = rbase + m * 16 + j;
        const int c = cbase + n * 16;
        float v = acc[m][n][j] + bias[c];
        if (RES) v += res[(size_t)r * N + c];
        if (RELU) v = fmaxf(v, 0.0f);
        if (OBF16) Cb[(size_t)r * N + c] = (short)f2bf(v);
        else       Cf[(size_t)r * N + c] = v;
      }
    }
  }
}

// ---------------- causal flash attention: 128-row Q tiles, 8 waves, reg-dbuf K/V ----------------
__global__ __launch_bounds__(512, 4)
void flash_attn(const short* __restrict__ qkv, const short* __restrict__ vt,
                short* __restrict__ o) {
  __shared__ short Ks[64 * 72];
  __shared__ short Vs[64 * 72];            // rows = d, cols = kv index
  __shared__ short Ps[8 * 16 * 76];
  const int t = threadIdx.x, lane = t & 63, w = t >> 6;
  const int qt = (int)gridDim.x - 1 - (int)blockIdx.x;   // longest-first
  const int bh = blockIdx.y;
  const int b = bh >> 4, hh = bh & 15;
  const int r8 = t >> 3, c8 = (t & 7) * 8;
  const float NEG_INF = -__builtin_inff();
  const size_t qk_base = (size_t)(b * 2048) * 3072 + hh * 64;
  const short* kptr = qkv + qk_base + 1024;
  const size_t vt_bh = (size_t)bh * 64 * 2048;
  const int wbase = qt * 128 + w * 16;
  const int nt = 2 * qt + 2;

  // Q fragments direct to registers (wave w owns rows wbase..wbase+15)
  bh8 aq[2];
  {
    const short* qrow = qkv + qk_base + (size_t)(wbase + (lane & 15)) * 3072 + (lane >> 4) * 8;
#pragma unroll
    for (int kk = 0; kk < 2; ++kk) aq[kk] = *(const bh8*)(qrow + kk * 32);
  }
  f4 Ofr[4] = {};
  float mr[4] = {NEG_INF, NEG_INF, NEG_INF, NEG_INF};
  float lsum[4] = {0.f, 0.f, 0.f, 0.f};

  // prologue: stage tile 0
  bh8 rk = *(const bh8*)(kptr + (size_t)r8 * 3072 + c8);
  bh8 rv = *(const bh8*)(vt + vt_bh + (size_t)r8 * 2048 + c8);
  *(bh8*)(&Ks[r8 * 72 + c8]) = rk;
  *(bh8*)(&Vs[r8 * 72 + c8]) = rv;

  for (int kt = 0; kt < nt; ++kt) {
    __syncthreads();                       // LDS tile kt visible
    if (kt + 1 < nt) {                     // issue next tile's loads early (T14)
      rk = *(const bh8*)(kptr + (size_t)((kt + 1) * 64 + r8) * 3072 + c8);
      rv = *(const bh8*)(vt + vt_bh + (size_t)r8 * 2048 + (kt + 1) * 64 + c8);
    }
    const bool skip = (kt * 64 > wbase + 15);   // tile fully masked for this wave
    if (!skip) {
      // S = Q K^T
      f4 sf[4] = {};
#pragma unroll
      for (int kk = 0; kk < 2; ++kk) {
#pragma unroll
        for (int n = 0; n < 4; ++n) {
          bh8 bk = *(const bh8*)(&Ks[(n * 16 + (lane & 15)) * 72 + kk * 32 + (lane >> 4) * 8]);
          sf[n] = __builtin_amdgcn_mfma_f32_16x16x32_bf16(aq[kk], bk, sf[n], 0, 0, 0);
        }
      }
      const float scale = 0.125f;
      if (kt * 64 + 63 > wbase) {          // straddling diagonal -> elementwise mask
#pragma unroll
        for (int n = 0; n < 4; ++n) {
          const int kp = kt * 64 + n * 16 + (lane & 15);
#pragma unroll
          for (int j = 0; j < 4; ++j) {
            const int qp = wbase + ((lane >> 4) << 2) + j;
            sf[n][j] = (kp > qp) ? NEG_INF : sf[n][j] * scale;
          }
        }
      } else {
#pragma unroll
        for (int n = 0; n < 4; ++n)
#pragma unroll
          for (int j = 0; j < 4; ++j) sf[n][j] *= scale;
      }
      // online softmax (rows live in 16-lane groups)
      float tm[4], al[4], rs[4];
#pragma unroll
      for (int j = 0; j < 4; ++j) {
        float mx = fmaxf(fmaxf(sf[0][j], sf[1][j]), fmaxf(sf[2][j], sf[3][j]));
#pragma unroll
        for (int mk = 1; mk < 16; mk <<= 1) mx = fmaxf(mx, __shfl_xor(mx, mk, 64));
        tm[j] = mx;
      }
#pragma unroll
      for (int j = 0; j < 4; ++j) {
        const float mn = fmaxf(mr[j], tm[j]);
        al[j] = __expf(mr[j] - mn);
        mr[j] = mn;
        rs[j] = 0.f;
      }
      f4 pf[4];
#pragma unroll
      for (int n = 0; n < 4; ++n)
#pragma unroll
        for (int j = 0; j < 4; ++j) {
          const float p = __expf(sf[n][j] - mr[j]);
          pf[n][j] = p;
          rs[j] += p;
        }
#pragma unroll
      for (int j = 0; j < 4; ++j) {
        float s = rs[j];
#pragma unroll
        for (int mk = 1; mk < 16; mk <<= 1) s += __shfl_xor(s, mk, 64);
        lsum[j] = lsum[j] * al[j] + s;
      }
#pragma unroll
      for (int n = 0; n < 4; ++n)
#pragma unroll
        for (int j = 0; j < 4; ++j) Ofr[n][j] *= al[j];
      // P -> per-wave LDS to reach A-fragment layout (stride 76: even bank spread)
      short* Pw = &Ps[w * 16 * 76];
#pragma unroll
      for (int n = 0; n < 4; ++n)
#pragma unroll
        for (int j = 0; j < 4; ++j)
          Pw[(((lane >> 4) << 2) + j) * 76 + n * 16 + (lane & 15)] = (short)f2bf(pf[n][j]);
      // O += P V
#pragma unroll
      for (int kk = 0; kk < 2; ++kk) {
        bh8 ap = *(const bh8*)(&Pw[(lane & 15) * 76 + kk * 32 + (lane >> 4) * 8]);
#pragma unroll
        for (int n = 0; n < 4; ++n) {
          bh8 bv = *(const bh8*)(&Vs[(n * 16 + (lane & 15)) * 72 + kk * 32 + (lane >> 4) * 8]);
          Ofr[n] = __builtin_amdgcn_mfma_f32_16x16x32_bf16(ap, bv, Ofr[n], 0, 0, 0);
        }
      }
    }
    __syncthreads();                       // all waves done reading LDS tile kt
    if (kt + 1 < nt) {                     // write prefetched tile kt+1
      *(bh8*)(&Ks[r8 * 72 + c8]) = rk;
      *(bh8*)(&Vs[r8 * 72 + c8]) = rv;
    }
  }
#pragma unroll
  for (int j = 0; j < 4; ++j) lsum[j] = 1.0f / lsum[j];
  const size_t orow0 = (size_t)b * 2048 + qt * 128 + w * 16 + ((lane >> 4) << 2);
#pragma unroll
  for (int n = 0; n < 4; ++n) {
    const int c = hh * 64 + n * 16 + (lane & 15);
#pragma unroll
    for (int j = 0; j < 4; ++j)
      o[(orow0 + j) * 1024 + c] = (short)f2bf(Ofr[n][j] * lsum[j]);
  }
}

extern "C" void kernel_launch(void* const* d_in, const int* in_sizes, int n_in,
                              void* d_out, int out_size, void* d_ws, size_t ws_size,
                              hipStream_t stream) {
  const float* x   = (const float*)d_in[0];
  const float* Wq  = (const float*)d_in[1];
  const float* bq  = (const float*)d_in[2];
  const float* Wk  = (const float*)d_in[3];
  const float* bk  = (const float*)d_in[4];
  const float* Wv  = (const float*)d_in[5];
  const float* bv  = (const float*)d_in[6];
  const float* Wo  = (const float*)d_in[7];
  const float* bo  = (const float*)d_in[8];
  const float* W1  = (const float*)d_in[9];
  const float* bf1 = (const float*)d_in[10];
  const float* W2  = (const float*)d_in[11];
  const float* bf2 = (const float*)d_in[12];
  const float* g1  = (const float*)d_in[13];
  const float* be1 = (const float*)d_in[14];
  const float* g2  = (const float*)d_in[15];
  const float* be2 = (const float*)d_in[16];
  float* out = (float*)d_out;

  char* ws = (char*)d_ws;
  const size_t MB = 1u << 20;
  short* h_ob  = (short*)ws;                  // 16 MB: LN out; later attn out; later LN2 out
  short* qkv   = (short*)(ws + 16 * MB);      // 48 MB [8192][3072]
  short* f1    = (short*)(ws + 16 * MB);      // 64 MB alias (qkv+vt, dead at FF time)
  short* vtb   = (short*)(ws + 64 * MB);      // 16 MB [bh][64][2048]
  short* wqkvb = (short*)(ws + 80 * MB);      // 6 MB
  short* wob   = (short*)(ws + 86 * MB);      // 2 MB
  short* w1b   = (short*)(ws + 88 * MB);      // 8 MB
  short* w2b   = (short*)(ws + 96 * MB);      // 8 MB
  float* ct    = (float*)(ws + 104 * MB);     // 256 KB
  float* st    = ct + 65536;                  // 256 KB
  float* bqkv  = st + 65536;                  // 12 KB
  float* x2    = out;                         // attention residual lives in d_out

  rope_table<<<256, 256, 0, stream>>>(ct, st);
  concat_bias<<<12, 256, 0, stream>>>(bq, bk, bv, bqkv);
  w2bf_all<<<dim3(4096, 6), 256, 0, stream>>>(Wq, Wk, Wv, Wo, W1, W2,
                                              wqkvb, wob, w1b, w2b);

  layernorm_bf<<<8192, 256, 0, stream>>>(x, g1, be1, h_ob);

  gemm_bt<0, 0, 1><<<dim3(64, 24), 256, 0, stream>>>(h_ob, wqkvb, bqkv, nullptr, qkv, nullptr, 8192, 3072, 1024);

  rope_apply<<<dim3(4096, 2), 256, 0, stream>>>(qkv, ct, st);

  v_transpose<<<dim3(32, 64), 256, 0, stream>>>(qkv, vtb);

  flash_attn<<<dim3(16, 64), 512, 0, stream>>>(qkv, vtb, h_ob);  // h dead -> reuse as ob

  gemm_bt<0, 1, 0><<<dim3(64, 8), 256, 0, stream>>>(h_ob, wob, bo, x, nullptr, x2, 8192, 1024, 1024);

  layernorm_bf<<<8192, 256, 0, stream>>>(x2, g2, be2, h_ob);     // ob dead -> reuse as h

  gemm_bt<1, 0, 1><<<dim3(64, 32), 256, 0, stream>>>(h_ob, w1b, bf1, nullptr, f1, nullptr, 8192, 4096, 1024);

  gemm_bt<0, 1, 0><<<dim3(64, 8), 256, 0, stream>>>(f1, w2b, bf2, x2, nullptr, out, 8192, 1024, 4096);
}

// Round 4
// 472.483 us; speedup vs baseline: 1.2900x; 1.2900x over previous
//
#include <hip/hip_runtime.h>

typedef __attribute__((ext_vector_type(8))) short bh8;
typedef __attribute__((ext_vector_type(4))) float f4;
typedef __attribute__((ext_vector_type(16))) float f16v;
typedef __attribute__((ext_vector_type(4))) unsigned int u4;

__device__ __forceinline__ unsigned short f2bf(float x) {
  unsigned int u = __float_as_uint(x);
  u += 0x7fffu + ((u >> 16) & 1u);
  return (unsigned short)(u >> 16);
}
__device__ __forceinline__ float bf2f(short x) {
  return __uint_as_float(((unsigned int)(unsigned short)x) << 16);
}
__device__ __forceinline__ unsigned cvtpk_bf16(float lo, float hi) {
  unsigned r;
  asm("v_cvt_pk_bf16_f32 %0, %1, %2" : "=v"(r) : "v"(lo), "v"(hi));
  return r;
}
__device__ __forceinline__ void gl_lds16(const short* g, short* l) {
  __builtin_amdgcn_global_load_lds(
      (const __attribute__((address_space(1))) unsigned int*)g,
      (__attribute__((address_space(3))) unsigned int*)l, 16, 0, 0);
}

// ---------------- RoPE table ----------------
__global__ __launch_bounds__(256)
void rope_table(float* __restrict__ ct, float* __restrict__ st) {
  const int idx = blockIdx.x * 256 + threadIdx.x;   // 65536 = 2048*32
  const int s = idx >> 5, j = idx & 31;
  const float invf = expf(-0.28782313662425574f * (float)j);  // 10000^(-j/32)
  const float f = (float)s * invf;
  ct[idx] = cosf(f);
  st[idx] = sinf(f);
}

// ---------------- bias concat for fused QKV ----------------
__global__ __launch_bounds__(256)
void concat_bias(const float* __restrict__ bq, const float* __restrict__ bk,
                 const float* __restrict__ bv, float* __restrict__ bqkv) {
  const int i = blockIdx.x * 256 + threadIdx.x;  // 3072
  bqkv[i] = (i < 1024) ? bq[i] : ((i < 2048) ? bk[i - 1024] : bv[i - 2048]);
}

// ---------------- all weights fp32 -> bf16 (QKV concatenated) ----------------
__global__ __launch_bounds__(256)
void w2bf_all(const float* __restrict__ Wq, const float* __restrict__ Wk,
              const float* __restrict__ Wv, const float* __restrict__ Wo,
              const float* __restrict__ W1, const float* __restrict__ W2,
              short* __restrict__ wqkvb, short* __restrict__ wob,
              short* __restrict__ w1b, short* __restrict__ w2b) {
  const int which = blockIdx.y;
  const float* src; short* dst; int n;
  switch (which) {
    case 0: src = Wq; dst = wqkvb;                 n = 1 << 20; break;
    case 1: src = Wk; dst = wqkvb + (1 << 20);     n = 1 << 20; break;
    case 2: src = Wv; dst = wqkvb + (2 << 20);     n = 1 << 20; break;
    case 3: src = Wo; dst = wob;                   n = 1 << 20; break;
    case 4: src = W1; dst = w1b;                   n = 1 << 22; break;
    default: src = W2; dst = w2b;                  n = 1 << 22; break;
  }
  const int i = (blockIdx.x * 256 + threadIdx.x) * 4;
  if (i >= n) return;
  f4 v = *(const f4*)(src + i);
#pragma unroll
  for (int j = 0; j < 4; ++j) dst[i + j] = (short)f2bf(v[j]);
}

// ---------------- LayerNorm (row=1024) ----------------
__global__ __launch_bounds__(256)
void layernorm_bf(const float* __restrict__ x, const float* __restrict__ g,
                  const float* __restrict__ be, short* __restrict__ out) {
  __shared__ float sb[4];
  const int row = blockIdx.x, t = threadIdx.x;
  const float* xr = x + (size_t)row * 1024;
  f4 v = *(const f4*)(xr + t * 4);
  float s = v[0] + v[1] + v[2] + v[3];
#pragma unroll
  for (int mk = 1; mk < 64; mk <<= 1) s += __shfl_xor(s, mk, 64);
  if ((t & 63) == 0) sb[t >> 6] = s;
  __syncthreads();
  const float mean = (sb[0] + sb[1] + sb[2] + sb[3]) * (1.0f / 1024.0f);
  __syncthreads();
  f4 d;
#pragma unroll
  for (int i = 0; i < 4; ++i) d[i] = v[i] - mean;
  float s2 = d[0] * d[0] + d[1] * d[1] + d[2] * d[2] + d[3] * d[3];
#pragma unroll
  for (int mk = 1; mk < 64; mk <<= 1) s2 += __shfl_xor(s2, mk, 64);
  if ((t & 63) == 0) sb[t >> 6] = s2;
  __syncthreads();
  const float var = (sb[0] + sb[1] + sb[2] + sb[3]) * (1.0f / 1024.0f);
  const float rstd = rsqrtf(var + 1e-5f);
  const f4 gg = *(const f4*)(g + t * 4);
  const f4 bb = *(const f4*)(be + t * 4);
#pragma unroll
  for (int i = 0; i < 4; ++i)
    out[(size_t)row * 1024 + t * 4 + i] = (short)f2bf(d[i] * rstd * gg[i] + bb[i]);
}

// ---------------- in-place RoPE on q|k inside qkv [8192,3072] ----------------
__global__ __launch_bounds__(256)
void rope_apply(short* __restrict__ qkv, const float* __restrict__ ct,
                const float* __restrict__ st) {
  const int off = blockIdx.y ? 1024 : 0;
  const int gid = blockIdx.x * 256 + threadIdx.x;  // 8192*128
  const int row = gid >> 7, chn = gid & 127;
  const int srow = row & 2047;
  const int col = chn * 8;
  const int j0 = (col & 63) >> 1;
  short* p = qkv + (size_t)row * 3072 + off + col;
  bh8 vv = *(const bh8*)p;
  bh8 r;
#pragma unroll
  for (int pp = 0; pp < 4; ++pp) {
    const float e = bf2f(vv[2 * pp]), od = bf2f(vv[2 * pp + 1]);
    const float c = ct[srow * 32 + j0 + pp], sn = st[srow * 32 + j0 + pp];
    r[2 * pp]     = (short)f2bf(e * c - od * sn);
    r[2 * pp + 1] = (short)f2bf(e * sn + od * c);
  }
  *(bh8*)p = r;
}

// ---------------- V transpose: qkv v-section -> vt[b,h,d,s] ----------------
__global__ __launch_bounds__(256)
void v_transpose(const short* __restrict__ qkv, short* __restrict__ vt) {
  __shared__ short tile[64][72];
  const int st = blockIdx.x, bh = blockIdx.y;
  const int b = bh >> 4, hh = bh & 15;
  const int t = threadIdx.x;
  const int r = t >> 3, c = (t & 7) * 8;
#pragma unroll
  for (int p = 0; p < 2; ++p) {
    const int s = st * 64 + p * 32 + r;
    bh8 vv = *(const bh8*)(qkv + ((size_t)b * 2048 + s) * 3072 + 2048 + hh * 64 + c);
    *(bh8*)(&tile[p * 32 + r][c]) = vv;
  }
  __syncthreads();
#pragma unroll
  for (int p = 0; p < 2; ++p) {
    const int d = p * 32 + r;
    bh8 ov;
#pragma unroll
    for (int i = 0; i < 8; ++i) ov[i] = tile[c + i][d];
    *(bh8*)(vt + ((size_t)bh * 64 + d) * 2048 + st * 64 + c) = ov;
  }
}

// ---------------- bf16 B^T GEMM (m97 structure): C = A[M,K]*Bw[N,K]^T + bias (+res)(+relu) ----------------
template <int RELU, int RES, int OBF16>
__global__ __launch_bounds__(256)
void gemm_bt(const short* __restrict__ A, const short* __restrict__ Bw,
             const float* __restrict__ bias, const float* __restrict__ res,
             short* __restrict__ Cb, float* __restrict__ Cf,
             int M, int N, int K) {
  __shared__ short As[128 * 32];
  __shared__ short Bs[128 * 32];
  const int t = threadIdx.x;
  const int lane = t & 63;
  const int w = t >> 6, wr = w >> 1, wc = w & 1;
  const int bm = blockIdx.x, bn = blockIdx.y;
  const int srow = lane >> 2;          // 0..15
  const int scol = (lane & 3) * 8;     // shorts
  f4 acc[4][4] = {};
  const short* Abase = A + (size_t)(bm * 128) * K;
  const short* Bbase = Bw + (size_t)(bn * 128) * K;
  for (int kt = 0; kt < K; kt += 32) {
#pragma unroll
    for (int i = 0; i < 2; ++i) {
      const int r = w * 32 + i * 16 + srow;
      gl_lds16(Abase + (size_t)r * K + kt + scol, &As[(w * 32 + i * 16) * 32]);
      gl_lds16(Bbase + (size_t)r * K + kt + scol, &Bs[(w * 32 + i * 16) * 32]);
    }
    __syncthreads();
    bh8 af[4], bf[4];
#pragma unroll
    for (int m = 0; m < 4; ++m)
      af[m] = *(const bh8*)(&As[(wr * 64 + m * 16 + (lane & 15)) * 32 + (lane >> 4) * 8]);
#pragma unroll
    for (int n = 0; n < 4; ++n)
      bf[n] = *(const bh8*)(&Bs[(wc * 64 + n * 16 + (lane & 15)) * 32 + (lane >> 4) * 8]);
#pragma unroll
    for (int m = 0; m < 4; ++m)
#pragma unroll
      for (int n = 0; n < 4; ++n)
        acc[m][n] = __builtin_amdgcn_mfma_f32_16x16x32_bf16(af[m], bf[n], acc[m][n], 0, 0, 0);
    __syncthreads();
  }
  const int rbase = bm * 128 + wr * 64 + ((lane >> 4) << 2);
  const int cbase = bn * 128 + wc * 64 + (lane & 15);
#pragma unroll
  for (int m = 0; m < 4; ++m) {
#pragma unroll
    for (int n = 0; n < 4; ++n) {
#pragma unroll
      for (int j = 0; j < 4; ++j) {
        const int r = rbase + m * 16 + j;
        const int c = cbase + n * 16;
        float v = acc[m][n][j] + bias[c];
        if (RES) v += res[(size_t)r * N + c];
        if (RELU) v = fmaxf(v, 0.0f);
        if (OBF16) Cb[(size_t)r * N + c] = (short)f2bf(v);
        else       Cf[(size_t)r * N + c] = v;
      }
    }
  }
}

// ---------------- causal flash attention: 8 warps x 32 q-rows, 32x32 MFMA, swapped QK^T ----------------
// S^T = mfma(K, Q): lane owns q-row (lane&31); softmax fully in-register.
// PV:  O^T = mfma(V^T, P^T): P B-fragment assembled via cvt_pk + shfl_xor(32).
__global__ __launch_bounds__(512, 2)
void flash_attn(const short* __restrict__ qkv, const short* __restrict__ vt,
                short* __restrict__ o) {
  __shared__ short lds[2 * 2 * 64 * 72];     // [buf][K|Vt][64][72]; reused as Ot[256][72]
  const int t = threadIdx.x, lane = t & 63, w = t >> 6;
  const int l31 = lane & 31, l5 = lane >> 5;
  // XCD-bijective work swizzle: 8 qt-blocks of one bh stay on one XCD; longest qt first.
  const int id = blockIdx.x;                 // 512 blocks
  const int wk = (id & 7) * 64 + (id >> 3);
  const int bh = wk >> 3;
  const int qt = 7 - (wk & 7);
  const int b = bh >> 4, hh = bh & 15;
  const int r8 = t >> 3, c8 = (t & 7) * 8;
  const float NEG_INF = -__builtin_inff();

  const short* kbase = qkv + (size_t)b * 2048 * 3072 + 1024 + hh * 64;
  const short* vbase = vt + ((size_t)bh * 64 + r8) * 2048;
  const int wq0 = qt * 256 + w * 32;         // warp's first q row (within batch seq)
  const int nt = 4 * qt + 4;

  // Q B-fragments in registers: qf[dk] = Q[q=wq0+l31][dk*16 + l5*8 + 0..7]
  bh8 qf[4];
  {
    const short* qrow = qkv + ((size_t)b * 2048 + wq0 + l31) * 3072 + hh * 64 + l5 * 8;
#pragma unroll
    for (int dk = 0; dk < 4; ++dk) qf[dk] = *(const bh8*)(qrow + dk * 16);
  }

  f16v o0 = {}, o1 = {};
  float mr = NEG_INF, lsum = 0.f;

  // prologue: stage tile 0 into buf 0
  {
    bh8 rk = *(const bh8*)(kbase + (size_t)r8 * 3072 + c8);
    bh8 rv = *(const bh8*)(vbase + c8);
    *(bh8*)(&lds[r8 * 72 + c8]) = rk;
    *(bh8*)(&lds[4608 + r8 * 72 + c8]) = rv;
  }

  for (int kt = 0; kt < nt; ++kt) {
    __syncthreads();                          // tile kt visible; prev reads of nxt done
    const int cur = kt & 1, nxt = cur ^ 1;
    bh8 rk, rv;
    const bool more = (kt + 1 < nt);
    if (more) {                               // issue next tile's loads early (T14)
      rk = *(const bh8*)(kbase + (size_t)((kt + 1) * 64 + r8) * 3072 + c8);
      rv = *(const bh8*)(vbase + (kt + 1) * 64 + c8);
    }
    const int kvb = kt * 64;
    if (kvb <= wq0 + 31) {                    // not fully masked for this warp
      const short* Kl = &lds[cur * 9216];
      const short* Vl = &lds[cur * 9216 + 4608];
      // S^T = K * Q
      f16v s0 = {}, s1 = {};
#pragma unroll
      for (int dk = 0; dk < 4; ++dk) {
        bh8 ka0 = *(const bh8*)(&Kl[l31 * 72 + dk * 16 + l5 * 8]);
        bh8 ka1 = *(const bh8*)(&Kl[(32 + l31) * 72 + dk * 16 + l5 * 8]);
        s0 = __builtin_amdgcn_mfma_f32_32x32x16_bf16(ka0, qf[dk], s0, 0, 0, 0);
        s1 = __builtin_amdgcn_mfma_f32_32x32x16_bf16(ka1, qf[dk], s1, 0, 0, 0);
      }
      // causal mask on diagonal-straddling tiles
      if (kvb + 63 > wq0) {
        const int qq = wq0 + l31;
        const int kvo = kvb + l5 * 4;
#pragma unroll
        for (int r = 0; r < 16; ++r) {
          const int kv0 = kvo + (r & 3) + 8 * (r >> 2);
          if (kv0 > qq) s0[r] = NEG_INF;
          if (kv0 + 32 > qq) s1[r] = NEG_INF;
        }
      }
      // online softmax: lane owns full q-row (own 32 vals + partner lane^32)
      float mx = s0[0];
#pragma unroll
      for (int r = 1; r < 16; ++r) mx = fmaxf(mx, s0[r]);
#pragma unroll
      for (int r = 0; r < 16; ++r) mx = fmaxf(mx, s1[r]);
      mx = fmaxf(mx, __shfl_xor(mx, 32, 64));
      const float mn = fmaxf(mr, mx);
      const float al = __expf((mr - mn) * 0.125f);
      mr = mn;
      float rsA = 0.f, rsB = 0.f;
#pragma unroll
      for (int r = 0; r < 16; ++r) {
        const float p0 = __expf((s0[r] - mn) * 0.125f);
        const float p1 = __expf((s1[r] - mn) * 0.125f);
        s0[r] = p0; s1[r] = p1;
        rsA += p0; rsB += p1;
      }
      float rs = rsA + rsB;
      rs += __shfl_xor(rs, 32, 64);
      lsum = lsum * al + rs;
#pragma unroll
      for (int r = 0; r < 16; ++r) { o0[r] *= al; o1[r] *= al; }
      // P values to flat regs (static indices)
      float pp[32];
#pragma unroll
      for (int r = 0; r < 16; ++r) { pp[r] = s0[r]; pp[16 + r] = s1[r]; }
      // O^T += V^T * P^T : per ks assemble B-frag (16 kv x 32 q) and 2 MFMA
      const bool lo32 = (l5 == 0);
#pragma unroll
      for (int ks = 0; ks < 4; ++ks) {
        const int base = (ks >> 1) * 16 + (ks & 1) * 8;
        const unsigned e0 = cvtpk_bf16(pp[base + 0], pp[base + 1]);
        const unsigned e1 = cvtpk_bf16(pp[base + 2], pp[base + 3]);
        const unsigned q0 = cvtpk_bf16(pp[base + 4], pp[base + 5]);
        const unsigned q1 = cvtpk_bf16(pp[base + 6], pp[base + 7]);
        const unsigned sel0 = lo32 ? q0 : e0;
        const unsigned sel1 = lo32 ? q1 : e1;
        const unsigned rx0 = (unsigned)__shfl_xor((int)sel0, 32, 64);
        const unsigned rx1 = (unsigned)__shfl_xor((int)sel1, 32, 64);
        u4 frag;
        frag[0] = lo32 ? e0 : rx0;
        frag[1] = lo32 ? e1 : rx1;
        frag[2] = lo32 ? rx0 : q0;
        frag[3] = lo32 ? rx1 : q1;
        const bh8 pb = *(const bh8*)&frag;
        bh8 va0 = *(const bh8*)(&Vl[l31 * 72 + ks * 16 + l5 * 8]);
        bh8 va1 = *(const bh8*)(&Vl[(32 + l31) * 72 + ks * 16 + l5 * 8]);
        o0 = __builtin_amdgcn_mfma_f32_32x32x16_bf16(va0, pb, o0, 0, 0, 0);
        o1 = __builtin_amdgcn_mfma_f32_32x32x16_bf16(va1, pb, o1, 0, 0, 0);
      }
    }
    if (more) {                               // write prefetched tile kt+1
      *(bh8*)(&lds[nxt * 9216 + r8 * 72 + c8]) = rk;
      *(bh8*)(&lds[nxt * 9216 + 4608 + r8 * 72 + c8]) = rv;
    }
  }

  // epilogue: normalize, stage O^T through LDS, coalesced store
  const float inv = 1.0f / lsum;
  __syncthreads();
  short* Ot = lds;                            // [256][72]
#pragma unroll
  for (int r = 0; r < 16; ++r) {
    const int d = (r & 3) + 8 * (r >> 2) + 4 * l5;
    Ot[(w * 32 + l31) * 72 + d]      = (short)f2bf(o0[r] * inv);
    Ot[(w * 32 + l31) * 72 + 32 + d] = (short)f2bf(o1[r] * inv);
  }
  __syncthreads();
  const int qrow = t >> 1, half = t & 1;
  short* orow = o + ((size_t)b * 2048 + qt * 256 + qrow) * 1024 + hh * 64 + half * 32;
#pragma unroll
  for (int i = 0; i < 4; ++i)
    *(bh8*)(orow + i * 8) = *(const bh8*)(&Ot[qrow * 72 + half * 32 + i * 8]);
}

extern "C" void kernel_launch(void* const* d_in, const int* in_sizes, int n_in,
                              void* d_out, int out_size, void* d_ws, size_t ws_size,
                              hipStream_t stream) {
  const float* x   = (const float*)d_in[0];
  const float* Wq  = (const float*)d_in[1];
  const float* bq  = (const float*)d_in[2];
  const float* Wk  = (const float*)d_in[3];
  const float* bk  = (const float*)d_in[4];
  const float* Wv  = (const float*)d_in[5];
  const float* bv  = (const float*)d_in[6];
  const float* Wo  = (const float*)d_in[7];
  const float* bo  = (const float*)d_in[8];
  const float* W1  = (const float*)d_in[9];
  const float* bf1 = (const float*)d_in[10];
  const float* W2  = (const float*)d_in[11];
  const float* bf2 = (const float*)d_in[12];
  const float* g1  = (const float*)d_in[13];
  const float* be1 = (const float*)d_in[14];
  const float* g2  = (const float*)d_in[15];
  const float* be2 = (const float*)d_in[16];
  float* out = (float*)d_out;

  char* ws = (char*)d_ws;
  const size_t MB = 1u << 20;
  short* h_ob  = (short*)ws;                  // 16 MB: LN out; later attn out; later LN2 out
  short* qkv   = (short*)(ws + 16 * MB);      // 48 MB [8192][3072]
  short* f1    = (short*)(ws + 16 * MB);      // 64 MB alias (qkv+vt, dead at FF time)
  short* vtb   = (short*)(ws + 64 * MB);      // 16 MB [bh][64][2048]
  short* wqkvb = (short*)(ws + 80 * MB);      // 6 MB
  short* wob   = (short*)(ws + 86 * MB);      // 2 MB
  short* w1b   = (short*)(ws + 88 * MB);      // 8 MB
  short* w2b   = (short*)(ws + 96 * MB);      // 8 MB
  float* ct    = (float*)(ws + 104 * MB);     // 256 KB
  float* st    = ct + 65536;                  // 256 KB
  float* bqkv  = st + 65536;                  // 12 KB
  float* x2    = out;                         // attention residual lives in d_out

  rope_table<<<256, 256, 0, stream>>>(ct, st);
  concat_bias<<<12, 256, 0, stream>>>(bq, bk, bv, bqkv);
  w2bf_all<<<dim3(4096, 6), 256, 0, stream>>>(Wq, Wk, Wv, Wo, W1, W2,
                                              wqkvb, wob, w1b, w2b);

  layernorm_bf<<<8192, 256, 0, stream>>>(x, g1, be1, h_ob);

  gemm_bt<0, 0, 1><<<dim3(64, 24), 256, 0, stream>>>(h_ob, wqkvb, bqkv, nullptr, qkv, nullptr, 8192, 3072, 1024);

  rope_apply<<<dim3(4096, 2), 256, 0, stream>>>(qkv, ct, st);

  v_transpose<<<dim3(32, 64), 256, 0, stream>>>(qkv, vtb);

  flash_attn<<<512, 512, 0, stream>>>(qkv, vtb, h_ob);   // h dead -> reuse as attn out

  gemm_bt<0, 1, 0><<<dim3(64, 8), 256, 0, stream>>>(h_ob, wob, bo, x, nullptr, x2, 8192, 1024, 1024);

  layernorm_bf<<<8192, 256, 0, stream>>>(x2, g2, be2, h_ob);     // ob dead -> reuse as h

  gemm_bt<1, 0, 1><<<dim3(64, 32), 256, 0, stream>>>(h_ob, w1b, bf1, nullptr, f1, nullptr, 8192, 4096, 1024);

  gemm_bt<0, 1, 0><<<dim3(64, 8), 256, 0, stream>>>(f1, w2b, bf2, x2, nullptr, out, 8192, 1024, 4096);
}

// Round 5
// 448.438 us; speedup vs baseline: 1.3592x; 1.0536x over previous
//
#include <hip/hip_runtime.h>

typedef __attribute__((ext_vector_type(8))) short bh8;
typedef __attribute__((ext_vector_type(4))) float f4;
typedef __attribute__((ext_vector_type(16))) float f16v;
typedef __attribute__((ext_vector_type(4))) unsigned int u4;

__device__ __forceinline__ unsigned short f2bf(float x) {
  unsigned int u = __float_as_uint(x);
  u += 0x7fffu + ((u >> 16) & 1u);
  return (unsigned short)(u >> 16);
}
__device__ __forceinline__ float bf2f(short x) {
  return __uint_as_float(((unsigned int)(unsigned short)x) << 16);
}
__device__ __forceinline__ unsigned cvtpk_bf16(float lo, float hi) {
  unsigned r;
  asm("v_cvt_pk_bf16_f32 %0, %1, %2" : "=v"(r) : "v"(lo), "v"(hi));
  return r;
}
__device__ __forceinline__ void gl_lds16(const short* g, short* l) {
  __builtin_amdgcn_global_load_lds(
      (const __attribute__((address_space(1))) unsigned int*)g,
      (__attribute__((address_space(3))) unsigned int*)l, 16, 0, 0);
}

#define VM4() asm volatile("s_waitcnt vmcnt(4)" ::: "memory")
#define VM0() asm volatile("s_waitcnt vmcnt(0)" ::: "memory")

// ---------------- RoPE table ----------------
__global__ __launch_bounds__(256)
void rope_table(float* __restrict__ ct, float* __restrict__ st) {
  const int idx = blockIdx.x * 256 + threadIdx.x;   // 65536 = 2048*32
  const int s = idx >> 5, j = idx & 31;
  const float invf = expf(-0.28782313662425574f * (float)j);  // 10000^(-j/32)
  const float f = (float)s * invf;
  ct[idx] = cosf(f);
  st[idx] = sinf(f);
}

// ---------------- bias concat for fused QKV ----------------
__global__ __launch_bounds__(256)
void concat_bias(const float* __restrict__ bq, const float* __restrict__ bk,
                 const float* __restrict__ bv, float* __restrict__ bqkv) {
  const int i = blockIdx.x * 256 + threadIdx.x;  // 3072
  bqkv[i] = (i < 1024) ? bq[i] : ((i < 2048) ? bk[i - 1024] : bv[i - 2048]);
}

// ---------------- all weights fp32 -> bf16 (QKV concatenated) ----------------
__global__ __launch_bounds__(256)
void w2bf_all(const float* __restrict__ Wq, const float* __restrict__ Wk,
              const float* __restrict__ Wv, const float* __restrict__ Wo,
              const float* __restrict__ W1, const float* __restrict__ W2,
              short* __restrict__ wqkvb, short* __restrict__ wob,
              short* __restrict__ w1b, short* __restrict__ w2b) {
  const int which = blockIdx.y;
  const float* src; short* dst; int n;
  switch (which) {
    case 0: src = Wq; dst = wqkvb;                 n = 1 << 20; break;
    case 1: src = Wk; dst = wqkvb + (1 << 20);     n = 1 << 20; break;
    case 2: src = Wv; dst = wqkvb + (2 << 20);     n = 1 << 20; break;
    case 3: src = Wo; dst = wob;                   n = 1 << 20; break;
    case 4: src = W1; dst = w1b;                   n = 1 << 22; break;
    default: src = W2; dst = w2b;                  n = 1 << 22; break;
  }
  const int i = (blockIdx.x * 256 + threadIdx.x) * 4;
  if (i >= n) return;
  f4 v = *(const f4*)(src + i);
#pragma unroll
  for (int j = 0; j < 4; ++j) dst[i + j] = (short)f2bf(v[j]);
}

// ---------------- LayerNorm (row=1024) ----------------
__global__ __launch_bounds__(256)
void layernorm_bf(const float* __restrict__ x, const float* __restrict__ g,
                  const float* __restrict__ be, short* __restrict__ out) {
  __shared__ float sb[4];
  const int row = blockIdx.x, t = threadIdx.x;
  const float* xr = x + (size_t)row * 1024;
  f4 v = *(const f4*)(xr + t * 4);
  float s = v[0] + v[1] + v[2] + v[3];
#pragma unroll
  for (int mk = 1; mk < 64; mk <<= 1) s += __shfl_xor(s, mk, 64);
  if ((t & 63) == 0) sb[t >> 6] = s;
  __syncthreads();
  const float mean = (sb[0] + sb[1] + sb[2] + sb[3]) * (1.0f / 1024.0f);
  __syncthreads();
  f4 d;
#pragma unroll
  for (int i = 0; i < 4; ++i) d[i] = v[i] - mean;
  float s2 = d[0] * d[0] + d[1] * d[1] + d[2] * d[2] + d[3] * d[3];
#pragma unroll
  for (int mk = 1; mk < 64; mk <<= 1) s2 += __shfl_xor(s2, mk, 64);
  if ((t & 63) == 0) sb[t >> 6] = s2;
  __syncthreads();
  const float var = (sb[0] + sb[1] + sb[2] + sb[3]) * (1.0f / 1024.0f);
  const float rstd = rsqrtf(var + 1e-5f);
  const f4 gg = *(const f4*)(g + t * 4);
  const f4 bb = *(const f4*)(be + t * 4);
#pragma unroll
  for (int i = 0; i < 4; ++i)
    out[(size_t)row * 1024 + t * 4 + i] = (short)f2bf(d[i] * rstd * gg[i] + bb[i]);
}

// ---------------- in-place RoPE on q|k inside qkv [8192,3072] ----------------
__global__ __launch_bounds__(256)
void rope_apply(short* __restrict__ qkv, const float* __restrict__ ct,
                const float* __restrict__ st) {
  const int off = blockIdx.y ? 1024 : 0;
  const int gid = blockIdx.x * 256 + threadIdx.x;  // 8192*128
  const int row = gid >> 7, chn = gid & 127;
  const int srow = row & 2047;
  const int col = chn * 8;
  const int j0 = (col & 63) >> 1;
  short* p = qkv + (size_t)row * 3072 + off + col;
  bh8 vv = *(const bh8*)p;
  bh8 r;
#pragma unroll
  for (int pp = 0; pp < 4; ++pp) {
    const float e = bf2f(vv[2 * pp]), od = bf2f(vv[2 * pp + 1]);
    const float c = ct[srow * 32 + j0 + pp], sn = st[srow * 32 + j0 + pp];
    r[2 * pp]     = (short)f2bf(e * c - od * sn);
    r[2 * pp + 1] = (short)f2bf(e * sn + od * c);
  }
  *(bh8*)p = r;
}

// ---------------- V transpose: qkv v-section -> vt[b,h,d,s] ----------------
__global__ __launch_bounds__(256)
void v_transpose(const short* __restrict__ qkv, short* __restrict__ vt) {
  __shared__ short tile[64][72];
  const int st = blockIdx.x, bh = blockIdx.y;
  const int b = bh >> 4, hh = bh & 15;
  const int t = threadIdx.x;
  const int r = t >> 3, c = (t & 7) * 8;
#pragma unroll
  for (int p = 0; p < 2; ++p) {
    const int s = st * 64 + p * 32 + r;
    bh8 vv = *(const bh8*)(qkv + ((size_t)b * 2048 + s) * 3072 + 2048 + hh * 64 + c);
    *(bh8*)(&tile[p * 32 + r][c]) = vv;
  }
  __syncthreads();
#pragma unroll
  for (int p = 0; p < 2; ++p) {
    const int d = p * 32 + r;
    bh8 ov;
#pragma unroll
    for (int i = 0; i < 8; ++i) ov[i] = tile[c + i][d];
    *(bh8*)(vt + ((size_t)bh * 64 + d) * 2048 + st * 64 + c) = ov;
  }
}

// ---------------- bf16 B^T GEMM (m97 structure, 128^2): C = A*Bw^T + bias (+res)(+relu) ----------------
template <int RELU, int RES, int OBF16>
__global__ __launch_bounds__(256)
void gemm_bt(const short* __restrict__ A, const short* __restrict__ Bw,
             const float* __restrict__ bias, const float* __restrict__ res,
             short* __restrict__ Cb, float* __restrict__ Cf,
             int M, int N, int K) {
  __shared__ short As[128 * 32];
  __shared__ short Bs[128 * 32];
  const int t = threadIdx.x;
  const int lane = t & 63;
  const int w = t >> 6, wr = w >> 1, wc = w & 1;
  const int bm = blockIdx.x, bn = blockIdx.y;
  const int srow = lane >> 2;          // 0..15
  const int scol = (lane & 3) * 8;     // shorts
  f4 acc[4][4] = {};
  const short* Abase = A + (size_t)(bm * 128) * K;
  const short* Bbase = Bw + (size_t)(bn * 128) * K;
  for (int kt = 0; kt < K; kt += 32) {
#pragma unroll
    for (int i = 0; i < 2; ++i) {
      const int r = w * 32 + i * 16 + srow;
      gl_lds16(Abase + (size_t)r * K + kt + scol, &As[(w * 32 + i * 16) * 32]);
      gl_lds16(Bbase + (size_t)r * K + kt + scol, &Bs[(w * 32 + i * 16) * 32]);
    }
    __syncthreads();
    bh8 af[4], bf[4];
#pragma unroll
    for (int m = 0; m < 4; ++m)
      af[m] = *(const bh8*)(&As[(wr * 64 + m * 16 + (lane & 15)) * 32 + (lane >> 4) * 8]);
#pragma unroll
    for (int n = 0; n < 4; ++n)
      bf[n] = *(const bh8*)(&Bs[(wc * 64 + n * 16 + (lane & 15)) * 32 + (lane >> 4) * 8]);
#pragma unroll
    for (int m = 0; m < 4; ++m)
#pragma unroll
      for (int n = 0; n < 4; ++n)
        acc[m][n] = __builtin_amdgcn_mfma_f32_16x16x32_bf16(af[m], bf[n], acc[m][n], 0, 0, 0);
    __syncthreads();
  }
  const int rbase = bm * 128 + wr * 64 + ((lane >> 4) << 2);
  const int cbase = bn * 128 + wc * 64 + (lane & 15);
#pragma unroll
  for (int m = 0; m < 4; ++m) {
#pragma unroll
    for (int n = 0; n < 4; ++n) {
#pragma unroll
      for (int j = 0; j < 4; ++j) {
        const int r = rbase + m * 16 + j;
        const int c = cbase + n * 16;
        float v = acc[m][n][j] + bias[c];
        if (RES) v += res[(size_t)r * N + c];
        if (RELU) v = fmaxf(v, 0.0f);
        if (OBF16) Cb[(size_t)r * N + c] = (short)f2bf(v);
        else       Cf[(size_t)r * N + c] = v;
      }
    }
  }
}

// ---------------- 256^2 8-phase bf16 B^T GEMM (T2+T3+T4+T5) ----------------
// 512 thr = 8 waves (2M x 4N). BK=64. LDS 128KB dbuf. XOR slot swizzle (slot ^= row&7)
// applied on both sides: pre-swizzled global source in staging + swizzled ds_read.
// Stage schedule per iteration (tiles e=2i in buf0, o=2i+1 in buf1):
//   P0: o.A half0 -> As[1]   P1: o.A half1      P2: (e+2).B h0 -> Bs[0]  P3: (e+2).B h1, vmcnt(4)
//   P4: (e+2).A h0 -> As[0]  P5: (e+2).A h1     P6: (e+3).B h0 -> Bs[1]  P7: (e+3).B h1, vmcnt(4)
// vmcnt sits BEFORE the phase-end barrier so all waves' staged data is published.
#define STG(dst, gbase, kt, half)                                              \
  {                                                                            \
    _Pragma("unroll") for (int cc = 0; cc < 2; ++cc) {                         \
      const int rr = (half) * 128 + cc * 64 + sr;                              \
      gl_lds16(gbase + (size_t)rr * K + (kt) * 64 + ssl * 8,                   \
               &dst[rr * 64 + (t & 7) * 8]);                                   \
    }                                                                          \
  }

#define PHASE(bf, q, STAGE_STMT, VMSTMT)                                       \
  {                                                                            \
    if ((q) == 0) {                                                            \
      _Pragma("unroll") for (int ni = 0; ni < 4; ++ni)                         \
      _Pragma("unroll") for (int kk = 0; kk < 2; ++kk)                         \
        bfrag[ni][kk] = *(const bh8*)(&Bs[bf][(wn * 64 + ni * 16 + (lane & 15)) * 64 + (((lane >> 4) + kk * 4) ^ (lane & 7)) * 8]); \
    }                                                                          \
    _Pragma("unroll") for (int j = 0; j < 2; ++j)                              \
    _Pragma("unroll") for (int kk = 0; kk < 2; ++kk)                           \
      af[j][kk] = *(const bh8*)(&As[bf][(wm * 128 + (2 * (q) + j) * 16 + (lane & 15)) * 64 + (((lane >> 4) + kk * 4) ^ (lane & 7)) * 8]); \
    STAGE_STMT;                                                                \
    __builtin_amdgcn_s_barrier();                                              \
    asm volatile("s_waitcnt lgkmcnt(0)" ::: "memory");                         \
    __builtin_amdgcn_sched_barrier(0);                                         \
    __builtin_amdgcn_s_setprio(1);                                             \
    _Pragma("unroll") for (int j = 0; j < 2; ++j)                              \
    _Pragma("unroll") for (int ni = 0; ni < 4; ++ni)                           \
    _Pragma("unroll") for (int kk = 0; kk < 2; ++kk)                           \
      acc[2 * (q) + j][ni] = __builtin_amdgcn_mfma_f32_16x16x32_bf16(          \
          af[j][kk], bfrag[ni][kk], acc[2 * (q) + j][ni], 0, 0, 0);            \
    __builtin_amdgcn_s_setprio(0);                                             \
    VMSTMT;                                                                    \
    __builtin_amdgcn_s_barrier();                                              \
  }

template <int RELU, int OBF16>
__global__ __launch_bounds__(512, 2)
void gemm256(const short* __restrict__ A, const short* __restrict__ Bw,
             const float* __restrict__ bias,
             short* __restrict__ Cb, float* __restrict__ Cf,
             int M, int N, int K) {
  __shared__ short As[2][256 * 64];
  __shared__ short Bs[2][256 * 64];
  const int t = threadIdx.x, lane = t & 63;
  const int w = t >> 6, wm = w >> 2, wn = w & 3;
  const int bm = blockIdx.x, bn = blockIdx.y;
  const short* Ab = A + (size_t)(bm * 256) * K;
  const short* Bb = Bw + (size_t)(bn * 256) * K;
  const int nkt = K >> 6;
  const int sr = t >> 3;                    // staging row within 64-row chunk
  const int ssl = (t & 7) ^ (sr & 7);       // pre-swizzled source slot
  f4 acc[8][4] = {};
  bh8 bfrag[4][2], af[2][2];

  // prologue: t0.B, t0.A, t1.B (12 loads); drain all but t1.B
  STG(Bs[0], Bb, 0, 0); STG(Bs[0], Bb, 0, 1);
  STG(As[0], Ab, 0, 0); STG(As[0], Ab, 0, 1);
  STG(Bs[1], Bb, 1, 0); STG(Bs[1], Bb, 1, 1);
  VM4();
  __builtin_amdgcn_s_barrier();

  for (int i2 = 0; i2 < nkt; i2 += 2) {
    const bool nf = (i2 + 2 < nkt);
    PHASE(0, 0, STG(As[1], Ab, i2 + 1, 0), );
    PHASE(0, 1, STG(As[1], Ab, i2 + 1, 1), );
    PHASE(0, 2, if (nf) STG(Bs[0], Bb, i2 + 2, 0), );
    PHASE(0, 3, if (nf) STG(Bs[0], Bb, i2 + 2, 1),
          if (nf) { VM4(); } else { VM0(); });
    PHASE(1, 0, if (nf) STG(As[0], Ab, i2 + 2, 0), );
    PHASE(1, 1, if (nf) STG(As[0], Ab, i2 + 2, 1), );
    PHASE(1, 2, if (nf) STG(Bs[1], Bb, i2 + 3, 0), );
    PHASE(1, 3, if (nf) STG(Bs[1], Bb, i2 + 3, 1), VM4());
  }

  const int rb = bm * 256 + wm * 128 + ((lane >> 4) << 2);
  const int cb = bn * 256 + wn * 64 + (lane & 15);
#pragma unroll
  for (int mi = 0; mi < 8; ++mi) {
#pragma unroll
    for (int ni = 0; ni < 4; ++ni) {
      const int c = cb + ni * 16;
      const float bi = bias[c];
#pragma unroll
      for (int jr = 0; jr < 4; ++jr) {
        const int r = rb + mi * 16 + jr;
        float v = acc[mi][ni][jr] + bi;
        if (RELU) v = fmaxf(v, 0.f);
        if (OBF16) Cb[(size_t)r * N + c] = (short)f2bf(v);
        else       Cf[(size_t)r * N + c] = v;
      }
    }
  }
}

// ---------------- causal flash attention: 8 warps x 32 q-rows, 32x32 MFMA, swapped QK^T ----------------
__global__ __launch_bounds__(512, 2)
void flash_attn(const short* __restrict__ qkv, const short* __restrict__ vt,
                short* __restrict__ o) {
  __shared__ short lds[2 * 2 * 64 * 72];     // [buf][K|Vt][64][72]; reused as Ot[256][72]
  const int t = threadIdx.x, lane = t & 63, w = t >> 6;
  const int l31 = lane & 31, l5 = lane >> 5;
  const int id = blockIdx.x;                 // 512 blocks
  const int wk = (id & 7) * 64 + (id >> 3);
  const int bh = wk >> 3;
  const int qt = 7 - (wk & 7);
  const int b = bh >> 4, hh = bh & 15;
  const int r8 = t >> 3, c8 = (t & 7) * 8;
  const float NEG_INF = -__builtin_inff();

  const short* kbase = qkv + (size_t)b * 2048 * 3072 + 1024 + hh * 64;
  const short* vbase = vt + ((size_t)bh * 64 + r8) * 2048;
  const int wq0 = qt * 256 + w * 32;
  const int nt = 4 * qt + 4;

  bh8 qf[4];
  {
    const short* qrow = qkv + ((size_t)b * 2048 + wq0 + l31) * 3072 + hh * 64 + l5 * 8;
#pragma unroll
    for (int dk = 0; dk < 4; ++dk) qf[dk] = *(const bh8*)(qrow + dk * 16);
  }

  f16v o0 = {}, o1 = {};
  float mr = NEG_INF, lsum = 0.f;

  {
    bh8 rk = *(const bh8*)(kbase + (size_t)r8 * 3072 + c8);
    bh8 rv = *(const bh8*)(vbase + c8);
    *(bh8*)(&lds[r8 * 72 + c8]) = rk;
    *(bh8*)(&lds[4608 + r8 * 72 + c8]) = rv;
  }

  for (int kt = 0; kt < nt; ++kt) {
    __syncthreads();
    const int cur = kt & 1, nxt = cur ^ 1;
    bh8 rk, rv;
    const bool more = (kt + 1 < nt);
    if (more) {
      rk = *(const bh8*)(kbase + (size_t)((kt + 1) * 64 + r8) * 3072 + c8);
      rv = *(const bh8*)(vbase + (kt + 1) * 64 + c8);
    }
    const int kvb = kt * 64;
    if (kvb <= wq0 + 31) {
      const short* Kl = &lds[cur * 9216];
      const short* Vl = &lds[cur * 9216 + 4608];
      f16v s0 = {}, s1 = {};
#pragma unroll
      for (int dk = 0; dk < 4; ++dk) {
        bh8 ka0 = *(const bh8*)(&Kl[l31 * 72 + dk * 16 + l5 * 8]);
        bh8 ka1 = *(const bh8*)(&Kl[(32 + l31) * 72 + dk * 16 + l5 * 8]);
        s0 = __builtin_amdgcn_mfma_f32_32x32x16_bf16(ka0, qf[dk], s0, 0, 0, 0);
        s1 = __builtin_amdgcn_mfma_f32_32x32x16_bf16(ka1, qf[dk], s1, 0, 0, 0);
      }
      if (kvb + 63 > wq0) {
        const int qq = wq0 + l31;
        const int kvo = kvb + l5 * 4;
#pragma unroll
        for (int r = 0; r < 16; ++r) {
          const int kv0 = kvo + (r & 3) + 8 * (r >> 2);
          if (kv0 > qq) s0[r] = NEG_INF;
          if (kv0 + 32 > qq) s1[r] = NEG_INF;
        }
      }
      float mx = s0[0];
#pragma unroll
      for (int r = 1; r < 16; ++r) mx = fmaxf(mx, s0[r]);
#pragma unroll
      for (int r = 0; r < 16; ++r) mx = fmaxf(mx, s1[r]);
      mx = fmaxf(mx, __shfl_xor(mx, 32, 64));
      const float mn = fmaxf(mr, mx);
      const float al = __expf((mr - mn) * 0.125f);
      mr = mn;
      float rsA = 0.f, rsB = 0.f;
#pragma unroll
      for (int r = 0; r < 16; ++r) {
        const float p0 = __expf((s0[r] - mn) * 0.125f);
        const float p1 = __expf((s1[r] - mn) * 0.125f);
        s0[r] = p0; s1[r] = p1;
        rsA += p0; rsB += p1;
      }
      float rs = rsA + rsB;
      rs += __shfl_xor(rs, 32, 64);
      lsum = lsum * al + rs;
#pragma unroll
      for (int r = 0; r < 16; ++r) { o0[r] *= al; o1[r] *= al; }
      float pp[32];
#pragma unroll
      for (int r = 0; r < 16; ++r) { pp[r] = s0[r]; pp[16 + r] = s1[r]; }
      const bool lo32 = (l5 == 0);
#pragma unroll
      for (int ks = 0; ks < 4; ++ks) {
        const int base = (ks >> 1) * 16 + (ks & 1) * 8;
        const unsigned e0 = cvtpk_bf16(pp[base + 0], pp[base + 1]);
        const unsigned e1 = cvtpk_bf16(pp[base + 2], pp[base + 3]);
        const unsigned q0 = cvtpk_bf16(pp[base + 4], pp[base + 5]);
        const unsigned q1 = cvtpk_bf16(pp[base + 6], pp[base + 7]);
        const unsigned sel0 = lo32 ? q0 : e0;
        const unsigned sel1 = lo32 ? q1 : e1;
        const unsigned rx0 = (unsigned)__shfl_xor((int)sel0, 32, 64);
        const unsigned rx1 = (unsigned)__shfl_xor((int)sel1, 32, 64);
        u4 frag;
        frag[0] = lo32 ? e0 : rx0;
        frag[1] = lo32 ? e1 : rx1;
        frag[2] = lo32 ? rx0 : q0;
        frag[3] = lo32 ? rx1 : q1;
        const bh8 pb = *(const bh8*)&frag;
        bh8 va0 = *(const bh8*)(&Vl[l31 * 72 + ks * 16 + l5 * 8]);
        bh8 va1 = *(const bh8*)(&Vl[(32 + l31) * 72 + ks * 16 + l5 * 8]);
        o0 = __builtin_amdgcn_mfma_f32_32x32x16_bf16(va0, pb, o0, 0, 0, 0);
        o1 = __builtin_amdgcn_mfma_f32_32x32x16_bf16(va1, pb, o1, 0, 0, 0);
      }
    }
    if (more) {
      *(bh8*)(&lds[nxt * 9216 + r8 * 72 + c8]) = rk;
      *(bh8*)(&lds[nxt * 9216 + 4608 + r8 * 72 + c8]) = rv;
    }
  }

  const float inv = 1.0f / lsum;
  __syncthreads();
  short* Ot = lds;
#pragma unroll
  for (int r = 0; r < 16; ++r) {
    const int d = (r & 3) + 8 * (r >> 2) + 4 * l5;
    Ot[(w * 32 + l31) * 72 + d]      = (short)f2bf(o0[r] * inv);
    Ot[(w * 32 + l31) * 72 + 32 + d] = (short)f2bf(o1[r] * inv);
  }
  __syncthreads();
  const int qrow = t >> 1, half = t & 1;
  short* orow = o + ((size_t)b * 2048 + qt * 256 + qrow) * 1024 + hh * 64 + half * 32;
#pragma unroll
  for (int i = 0; i < 4; ++i)
    *(bh8*)(orow + i * 8) = *(const bh8*)(&Ot[qrow * 72 + half * 32 + i * 8]);
}

extern "C" void kernel_launch(void* const* d_in, const int* in_sizes, int n_in,
                              void* d_out, int out_size, void* d_ws, size_t ws_size,
                              hipStream_t stream) {
  const float* x   = (const float*)d_in[0];
  const float* Wq  = (const float*)d_in[1];
  const float* bq  = (const float*)d_in[2];
  const float* Wk  = (const float*)d_in[3];
  const float* bk  = (const float*)d_in[4];
  const float* Wv  = (const float*)d_in[5];
  const float* bv  = (const float*)d_in[6];
  const float* Wo  = (const float*)d_in[7];
  const float* bo  = (const float*)d_in[8];
  const float* W1  = (const float*)d_in[9];
  const float* bf1 = (const float*)d_in[10];
  const float* W2  = (const float*)d_in[11];
  const float* bf2 = (const float*)d_in[12];
  const float* g1  = (const float*)d_in[13];
  const float* be1 = (const float*)d_in[14];
  const float* g2  = (const float*)d_in[15];
  const float* be2 = (const float*)d_in[16];
  float* out = (float*)d_out;

  char* ws = (char*)d_ws;
  const size_t MB = 1u << 20;
  short* h_ob  = (short*)ws;                  // 16 MB: LN out; later attn out; later LN2 out
  short* qkv   = (short*)(ws + 16 * MB);      // 48 MB [8192][3072]
  short* f1    = (short*)(ws + 16 * MB);      // 64 MB alias (qkv+vt, dead at FF time)
  short* vtb   = (short*)(ws + 64 * MB);      // 16 MB [bh][64][2048]
  short* wqkvb = (short*)(ws + 80 * MB);      // 6 MB
  short* wob   = (short*)(ws + 86 * MB);      // 2 MB
  short* w1b   = (short*)(ws + 88 * MB);      // 8 MB
  short* w2b   = (short*)(ws + 96 * MB);      // 8 MB
  float* ct    = (float*)(ws + 104 * MB);     // 256 KB
  float* st    = ct + 65536;                  // 256 KB
  float* bqkv  = st + 65536;                  // 12 KB
  float* x2    = out;

  rope_table<<<256, 256, 0, stream>>>(ct, st);
  concat_bias<<<12, 256, 0, stream>>>(bq, bk, bv, bqkv);
  w2bf_all<<<dim3(4096, 6), 256, 0, stream>>>(Wq, Wk, Wv, Wo, W1, W2,
                                              wqkvb, wob, w1b, w2b);

  layernorm_bf<<<8192, 256, 0, stream>>>(x, g1, be1, h_ob);

  gemm256<0, 1><<<dim3(32, 12), 512, 0, stream>>>(h_ob, wqkvb, bqkv, qkv, nullptr, 8192, 3072, 1024);

  rope_apply<<<dim3(4096, 2), 256, 0, stream>>>(qkv, ct, st);

  v_transpose<<<dim3(32, 64), 256, 0, stream>>>(qkv, vtb);

  flash_attn<<<512, 512, 0, stream>>>(qkv, vtb, h_ob);

  gemm_bt<0, 1, 0><<<dim3(64, 8), 256, 0, stream>>>(h_ob, wob, bo, x, nullptr, x2, 8192, 1024, 1024);

  layernorm_bf<<<8192, 256, 0, stream>>>(x2, g2, be2, h_ob);

  gemm256<1, 1><<<dim3(32, 16), 512, 0, stream>>>(h_ob, w1b, bf1, f1, nullptr, 8192, 4096, 1024);

  gemm_bt<0, 1, 0><<<dim3(64, 8), 256, 0, stream>>>(f1, w2b, bf2, x2, nullptr, out, 8192, 1024, 4096);
}

// Round 6
// 397.392 us; speedup vs baseline: 1.5338x; 1.1285x over previous
//
#include <hip/hip_runtime.h>

typedef __attribute__((ext_vector_type(8))) short bh8;
typedef __attribute__((ext_vector_type(4))) float f4;
typedef __attribute__((ext_vector_type(16))) float f16v;
typedef __attribute__((ext_vector_type(4))) unsigned int u4;

__device__ __forceinline__ unsigned short f2bf(float x) {
  unsigned int u = __float_as_uint(x);
  u += 0x7fffu + ((u >> 16) & 1u);
  return (unsigned short)(u >> 16);
}
__device__ __forceinline__ float bf2f(short x) {
  return __uint_as_float(((unsigned int)(unsigned short)x) << 16);
}
__device__ __forceinline__ unsigned cvtpk_bf16(float lo, float hi) {
  unsigned r;
  asm("v_cvt_pk_bf16_f32 %0, %1, %2" : "=v"(r) : "v"(lo), "v"(hi));
  return r;
}
__device__ __forceinline__ void gl_lds16(const short* g, short* l) {
  __builtin_amdgcn_global_load_lds(
      (const __attribute__((address_space(1))) unsigned int*)g,
      (__attribute__((address_space(3))) unsigned int*)l, 16, 0, 0);
}

#define VM4() asm volatile("s_waitcnt vmcnt(4)" ::: "memory")
#define VM0() asm volatile("s_waitcnt vmcnt(0)" ::: "memory")

// ---------------- RoPE table ----------------
__global__ __launch_bounds__(256)
void rope_table(float* __restrict__ ct, float* __restrict__ st) {
  const int idx = blockIdx.x * 256 + threadIdx.x;   // 65536 = 2048*32
  const int s = idx >> 5, j = idx & 31;
  const float invf = expf(-0.28782313662425574f * (float)j);  // 10000^(-j/32)
  const float f = (float)s * invf;
  ct[idx] = cosf(f);
  st[idx] = sinf(f);
}

// ---------------- bias concat for fused QKV ----------------
__global__ __launch_bounds__(256)
void concat_bias(const float* __restrict__ bq, const float* __restrict__ bk,
                 const float* __restrict__ bv, float* __restrict__ bqkv) {
  const int i = blockIdx.x * 256 + threadIdx.x;  // 3072
  bqkv[i] = (i < 1024) ? bq[i] : ((i < 2048) ? bk[i - 1024] : bv[i - 2048]);
}

// ---------------- all weights fp32 -> bf16 (QKV concatenated) ----------------
__global__ __launch_bounds__(256)
void w2bf_all(const float* __restrict__ Wq, const float* __restrict__ Wk,
              const float* __restrict__ Wv, const float* __restrict__ Wo,
              const float* __restrict__ W1, const float* __restrict__ W2,
              short* __restrict__ wqkvb, short* __restrict__ wob,
              short* __restrict__ w1b, short* __restrict__ w2b) {
  const int which = blockIdx.y;
  const float* src; short* dst; int n;
  switch (which) {
    case 0: src = Wq; dst = wqkvb;                 n = 1 << 20; break;
    case 1: src = Wk; dst = wqkvb + (1 << 20);     n = 1 << 20; break;
    case 2: src = Wv; dst = wqkvb + (2 << 20);     n = 1 << 20; break;
    case 3: src = Wo; dst = wob;                   n = 1 << 20; break;
    case 4: src = W1; dst = w1b;                   n = 1 << 22; break;
    default: src = W2; dst = w2b;                  n = 1 << 22; break;
  }
  const int i = (blockIdx.x * 256 + threadIdx.x) * 4;
  if (i >= n) return;
  f4 v = *(const f4*)(src + i);
#pragma unroll
  for (int j = 0; j < 4; ++j) dst[i + j] = (short)f2bf(v[j]);
}

// ---------------- LayerNorm (row=1024) ----------------
__global__ __launch_bounds__(256)
void layernorm_bf(const float* __restrict__ x, const float* __restrict__ g,
                  const float* __restrict__ be, short* __restrict__ out) {
  __shared__ float sb[4];
  const int row = blockIdx.x, t = threadIdx.x;
  const float* xr = x + (size_t)row * 1024;
  f4 v = *(const f4*)(xr + t * 4);
  float s = v[0] + v[1] + v[2] + v[3];
#pragma unroll
  for (int mk = 1; mk < 64; mk <<= 1) s += __shfl_xor(s, mk, 64);
  if ((t & 63) == 0) sb[t >> 6] = s;
  __syncthreads();
  const float mean = (sb[0] + sb[1] + sb[2] + sb[3]) * (1.0f / 1024.0f);
  __syncthreads();
  f4 d;
#pragma unroll
  for (int i = 0; i < 4; ++i) d[i] = v[i] - mean;
  float s2 = d[0] * d[0] + d[1] * d[1] + d[2] * d[2] + d[3] * d[3];
#pragma unroll
  for (int mk = 1; mk < 64; mk <<= 1) s2 += __shfl_xor(s2, mk, 64);
  if ((t & 63) == 0) sb[t >> 6] = s2;
  __syncthreads();
  const float var = (sb[0] + sb[1] + sb[2] + sb[3]) * (1.0f / 1024.0f);
  const float rstd = rsqrtf(var + 1e-5f);
  const f4 gg = *(const f4*)(g + t * 4);
  const f4 bb = *(const f4*)(be + t * 4);
#pragma unroll
  for (int i = 0; i < 4; ++i)
    out[(size_t)row * 1024 + t * 4 + i] = (short)f2bf(d[i] * rstd * gg[i] + bb[i]);
}

// ---------------- in-place RoPE on q|k inside qkv [8192,3072] ----------------
__global__ __launch_bounds__(256)
void rope_apply(short* __restrict__ qkv, const float* __restrict__ ct,
                const float* __restrict__ st) {
  const int off = blockIdx.y ? 1024 : 0;
  const int gid = blockIdx.x * 256 + threadIdx.x;  // 8192*128
  const int row = gid >> 7, chn = gid & 127;
  const int srow = row & 2047;
  const int col = chn * 8;
  const int j0 = (col & 63) >> 1;
  short* p = qkv + (size_t)row * 3072 + off + col;
  bh8 vv = *(const bh8*)p;
  bh8 r;
#pragma unroll
  for (int pp = 0; pp < 4; ++pp) {
    const float e = bf2f(vv[2 * pp]), od = bf2f(vv[2 * pp + 1]);
    const float c = ct[srow * 32 + j0 + pp], sn = st[srow * 32 + j0 + pp];
    r[2 * pp]     = (short)f2bf(e * c - od * sn);
    r[2 * pp + 1] = (short)f2bf(e * sn + od * c);
  }
  *(bh8*)p = r;
}

// ---------------- V transpose: qkv v-section -> vt[b,h,d,s] ----------------
__global__ __launch_bounds__(256)
void v_transpose(const short* __restrict__ qkv, short* __restrict__ vt) {
  __shared__ short tile[64][72];
  const int st = blockIdx.x, bh = blockIdx.y;
  const int b = bh >> 4, hh = bh & 15;
  const int t = threadIdx.x;
  const int r = t >> 3, c = (t & 7) * 8;
#pragma unroll
  for (int p = 0; p < 2; ++p) {
    const int s = st * 64 + p * 32 + r;
    bh8 vv = *(const bh8*)(qkv + ((size_t)b * 2048 + s) * 3072 + 2048 + hh * 64 + c);
    *(bh8*)(&tile[p * 32 + r][c]) = vv;
  }
  __syncthreads();
#pragma unroll
  for (int p = 0; p < 2; ++p) {
    const int d = p * 32 + r;
    bh8 ov;
#pragma unroll
    for (int i = 0; i < 8; ++i) ov[i] = tile[c + i][d];
    *(bh8*)(vt + ((size_t)bh * 64 + d) * 2048 + st * 64 + c) = ov;
  }
}

// ---------------- 8-phase bf16 B^T GEMM (T2+T3+T4+T5), BM in {128,256}, BN=256 ----------------
// 512 thr = 8 waves (2M x 4N). BK=64. Double-buffered LDS. XOR slot swizzle (slot ^= row&7)
// applied both-sides: pre-swizzled global source + swizzled ds_read (rule #21).
// vmcnt(4) derivation holds for both BM: at P3-end outstanding = oddA + nextB(4 ops);
// wait oddA -> 4 left. At P7-end outstanding = nextA + nextB2(4); wait nextA -> 4 left.
#define STG(dst, gbase, kt, half)                                              \
  {                                                                            \
    _Pragma("unroll") for (int cc = 0; cc < 2; ++cc) {                         \
      const int rr = (half) * 128 + cc * 64 + sr;                              \
      gl_lds16(gbase + (size_t)rr * K + (kt) * 64 + ssl * 8,                   \
               &dst[rr * 64 + (t & 7) * 8]);                                   \
    }                                                                          \
  }

#define PHASE(bf, q, STAGE_STMT, VMSTMT)                                       \
  {                                                                            \
    if ((q) == 0) {                                                            \
      _Pragma("unroll") for (int ni = 0; ni < 4; ++ni)                         \
      _Pragma("unroll") for (int kk = 0; kk < 2; ++kk)                         \
        bfrag[ni][kk] = *(const bh8*)(&Bs[bf][(wn * 64 + ni * 16 + (lane & 15)) * 64 + (((lane >> 4) + kk * 4) ^ (lane & 7)) * 8]); \
    }                                                                          \
    _Pragma("unroll") for (int j = 0; j < MFR; ++j)                            \
    _Pragma("unroll") for (int kk = 0; kk < 2; ++kk)                           \
      af[j][kk] = *(const bh8*)(&As[bf][(wm * MROWS + (MFR * (q) + j) * 16 + (lane & 15)) * 64 + (((lane >> 4) + kk * 4) ^ (lane & 7)) * 8]); \
    STAGE_STMT;                                                                \
    __builtin_amdgcn_s_barrier();                                              \
    asm volatile("s_waitcnt lgkmcnt(0)" ::: "memory");                         \
    __builtin_amdgcn_sched_barrier(0);                                         \
    __builtin_amdgcn_s_setprio(1);                                             \
    _Pragma("unroll") for (int j = 0; j < MFR; ++j)                            \
    _Pragma("unroll") for (int ni = 0; ni < 4; ++ni)                           \
    _Pragma("unroll") for (int kk = 0; kk < 2; ++kk)                           \
      acc[MFR * (q) + j][ni] = __builtin_amdgcn_mfma_f32_16x16x32_bf16(        \
          af[j][kk], bfrag[ni][kk], acc[MFR * (q) + j][ni], 0, 0, 0);          \
    __builtin_amdgcn_s_setprio(0);                                             \
    VMSTMT;                                                                    \
    __builtin_amdgcn_s_barrier();                                              \
  }

template <int BM, int RELU, int RES, int OBF16>
__global__ __launch_bounds__(512, 2)
void gemm256(const short* __restrict__ A, const short* __restrict__ Bw,
             const float* __restrict__ bias, const float* __restrict__ res,
             short* __restrict__ Cb, float* __restrict__ Cf,
             int M, int N, int K) {
  constexpr int MFR = BM / 128;     // m-frags per phase
  constexpr int MROWS = BM / 2;     // rows per M-wave
  __shared__ short As[2][BM * 64];
  __shared__ short Bs[2][256 * 64];
  const int t = threadIdx.x, lane = t & 63;
  const int w = t >> 6, wm = w >> 2, wn = w & 3;
  // 1D grid + bijective XCD remap (gridDim.x % 8 == 0 for all our shapes)
  const int nwg = gridDim.x, cpx = nwg >> 3;
  int flat = blockIdx.x;
  flat = (flat & 7) * cpx + (flat >> 3);
  const int nbm = M / BM;
  const int bm = flat % nbm, bn = flat / nbm;
  const short* Ab = A + (size_t)(bm * BM) * K;
  const short* Bb = Bw + (size_t)(bn * 256) * K;
  const int nkt = K >> 6;
  const int sr = t >> 3;                    // staging row within 64-row chunk
  const int ssl = (t & 7) ^ (sr & 7);       // pre-swizzled source slot
  f4 acc[4 * MFR][4] = {};
  bh8 bfrag[4][2], af[MFR][2];

  // prologue: t0.B, t0.A, t1.B; drain all but t1.B (4 ops) -> vmcnt(4)
  STG(Bs[0], Bb, 0, 0); STG(Bs[0], Bb, 0, 1);
  if (BM == 256) { STG(As[0], Ab, 0, 0); STG(As[0], Ab, 0, 1); }
  else           { STG(As[0], Ab, 0, 0); }
  STG(Bs[1], Bb, 1, 0); STG(Bs[1], Bb, 1, 1);
  VM4();
  __builtin_amdgcn_s_barrier();

  for (int i2 = 0; i2 < nkt; i2 += 2) {
    const bool nf = (i2 + 2 < nkt);
    PHASE(0, 0, STG(As[1], Ab, i2 + 1, 0), );
    PHASE(0, 1, if (BM == 256) STG(As[1], Ab, i2 + 1, 1), );
    PHASE(0, 2, if (nf) STG(Bs[0], Bb, i2 + 2, 0), );
    PHASE(0, 3, if (nf) STG(Bs[0], Bb, i2 + 2, 1),
          if (nf) { VM4(); } else { VM0(); });
    PHASE(1, 0, if (nf) STG(As[0], Ab, i2 + 2, 0), );
    PHASE(1, 1, if (nf && BM == 256) STG(As[0], Ab, i2 + 2, 1), );
    PHASE(1, 2, if (nf) STG(Bs[1], Bb, i2 + 3, 0), );
    PHASE(1, 3, if (nf) STG(Bs[1], Bb, i2 + 3, 1), VM4());
  }

  const int rb = bm * BM + wm * MROWS + ((lane >> 4) << 2);
  const int cb = bn * 256 + wn * 64 + (lane & 15);
#pragma unroll
  for (int mi = 0; mi < 4 * MFR; ++mi) {
#pragma unroll
    for (int ni = 0; ni < 4; ++ni) {
      const int c = cb + ni * 16;
      const float bi = bias[c];
#pragma unroll
      for (int jr = 0; jr < 4; ++jr) {
        const int r = rb + mi * 16 + jr;
        float v = acc[mi][ni][jr] + bi;
        if (RES) v += res[(size_t)r * N + c];
        if (RELU) v = fmaxf(v, 0.f);
        if (OBF16) Cb[(size_t)r * N + c] = (short)f2bf(v);
        else       Cf[(size_t)r * N + c] = v;
      }
    }
  }
}

// ---------------- causal flash attention: uniform-work blocks (qt paired with 7-qt) ----------------
// 8 warps x 32 q-rows, 32x32 MFMA, swapped QK^T, in-register softmax, defer-max (T13).
__global__ __launch_bounds__(512, 2)
void flash_attn(const short* __restrict__ qkv, const short* __restrict__ vt,
                short* __restrict__ o) {
  __shared__ short lds[2 * 2 * 64 * 72];     // [buf][K|Vt][64][72]; reused as Ot[256][72]
  const int t = threadIdx.x, lane = t & 63, w = t >> 6;
  const int l31 = lane & 31, l5 = lane >> 5;
  const int id = blockIdx.x;                 // 256 blocks, uniform work
  const int xcd = id & 7, y = id >> 3;       // 8 bh per XCD for K/V L2 locality
  const int bh = xcd * 8 + (y >> 2);
  const int pr = y & 3;                      // pass qt pair: (7-pr, pr) -> 36 steps total
  const int b = bh >> 4, hh = bh & 15;
  const int r8 = t >> 3, c8 = (t & 7) * 8;
  const float NEG_INF = -__builtin_inff();

  const short* kbase = qkv + (size_t)b * 2048 * 3072 + 1024 + hh * 64;
  const short* vbase = vt + ((size_t)bh * 64 + r8) * 2048;

  for (int pass = 0; pass < 2; ++pass) {
    const int qt = pass ? pr : 7 - pr;
    const int wq0 = qt * 256 + w * 32;
    const int nt = 4 * qt + 4;

    bh8 qf[4];
    {
      const short* qrow = qkv + ((size_t)b * 2048 + wq0 + l31) * 3072 + hh * 64 + l5 * 8;
#pragma unroll
      for (int dk = 0; dk < 4; ++dk) qf[dk] = *(const bh8*)(qrow + dk * 16);
    }
    f16v o0 = {}, o1 = {};
    float mr = NEG_INF, lsum = 0.f;

    __syncthreads();                          // LDS free (prev pass epilogue done)
    {
      bh8 rk = *(const bh8*)(kbase + (size_t)r8 * 3072 + c8);
      bh8 rv = *(const bh8*)(vbase + c8);
      *(bh8*)(&lds[r8 * 72 + c8]) = rk;
      *(bh8*)(&lds[4608 + r8 * 72 + c8]) = rv;
    }

    for (int kt = 0; kt < nt; ++kt) {
      __syncthreads();
      const int cur = kt & 1, nxt = cur ^ 1;
      bh8 rk, rv;
      const bool more = (kt + 1 < nt);
      if (more) {                             // issue next tile's loads early (T14)
        rk = *(const bh8*)(kbase + (size_t)((kt + 1) * 64 + r8) * 3072 + c8);
        rv = *(const bh8*)(vbase + (kt + 1) * 64 + c8);
      }
      const int kvb = kt * 64;
      if (kvb <= wq0 + 31) {
        const short* Kl = &lds[cur * 9216];
        const short* Vl = &lds[cur * 9216 + 4608];
        f16v s0 = {}, s1 = {};
#pragma unroll
        for (int dk = 0; dk < 4; ++dk) {
          bh8 ka0 = *(const bh8*)(&Kl[l31 * 72 + dk * 16 + l5 * 8]);
          bh8 ka1 = *(const bh8*)(&Kl[(32 + l31) * 72 + dk * 16 + l5 * 8]);
          s0 = __builtin_amdgcn_mfma_f32_32x32x16_bf16(ka0, qf[dk], s0, 0, 0, 0);
          s1 = __builtin_amdgcn_mfma_f32_32x32x16_bf16(ka1, qf[dk], s1, 0, 0, 0);
        }
        if (kvb + 63 > wq0) {
          const int qq = wq0 + l31;
          const int kvo = kvb + l5 * 4;
#pragma unroll
          for (int r = 0; r < 16; ++r) {
            const int kv0 = kvo + (r & 3) + 8 * (r >> 2);
            if (kv0 > qq) s0[r] = NEG_INF;
            if (kv0 + 32 > qq) s1[r] = NEG_INF;
          }
        }
        float mx = s0[0];
#pragma unroll
        for (int r = 1; r < 16; ++r) mx = fmaxf(mx, s0[r]);
#pragma unroll
        for (int r = 0; r < 16; ++r) mx = fmaxf(mx, s1[r]);
        mx = fmaxf(mx, __shfl_xor(mx, 32, 64));
        // defer-max (T13): skip O-rescale when max grew by <= 8 (P bounded by e)
        const bool keep = __all(mx <= mr + 8.0f);
        float mn, al;
        if (keep) { mn = mr; al = 1.0f; }
        else {
          mn = fmaxf(mr, mx);
          al = __expf((mr - mn) * 0.125f);
          mr = mn;
        }
        float rsA = 0.f, rsB = 0.f;
#pragma unroll
        for (int r = 0; r < 16; ++r) {
          const float p0 = __expf((s0[r] - mn) * 0.125f);
          const float p1 = __expf((s1[r] - mn) * 0.125f);
          s0[r] = p0; s1[r] = p1;
          rsA += p0; rsB += p1;
        }
        float rs = rsA + rsB;
        rs += __shfl_xor(rs, 32, 64);
        if (keep) {
          lsum += rs;
        } else {
          lsum = lsum * al + rs;
#pragma unroll
          for (int r = 0; r < 16; ++r) { o0[r] *= al; o1[r] *= al; }
        }
        float pp[32];
#pragma unroll
        for (int r = 0; r < 16; ++r) { pp[r] = s0[r]; pp[16 + r] = s1[r]; }
        const bool lo32 = (l5 == 0);
#pragma unroll
        for (int ks = 0; ks < 4; ++ks) {
          const int base = (ks >> 1) * 16 + (ks & 1) * 8;
          const unsigned e0 = cvtpk_bf16(pp[base + 0], pp[base + 1]);
          const unsigned e1 = cvtpk_bf16(pp[base + 2], pp[base + 3]);
          const unsigned q0 = cvtpk_bf16(pp[base + 4], pp[base + 5]);
          const unsigned q1 = cvtpk_bf16(pp[base + 6], pp[base + 7]);
          const unsigned sel0 = lo32 ? q0 : e0;
          const unsigned sel1 = lo32 ? q1 : e1;
          const unsigned rx0 = (unsigned)__shfl_xor((int)sel0, 32, 64);
          const unsigned rx1 = (unsigned)__shfl_xor((int)sel1, 32, 64);
          u4 frag;
          frag[0] = lo32 ? e0 : rx0;
          frag[1] = lo32 ? e1 : rx1;
          frag[2] = lo32 ? rx0 : q0;
          frag[3] = lo32 ? rx1 : q1;
          const bh8 pb = *(const bh8*)&frag;
          bh8 va0 = *(const bh8*)(&Vl[l31 * 72 + ks * 16 + l5 * 8]);
          bh8 va1 = *(const bh8*)(&Vl[(32 + l31) * 72 + ks * 16 + l5 * 8]);
          o0 = __builtin_amdgcn_mfma_f32_32x32x16_bf16(va0, pb, o0, 0, 0, 0);
          o1 = __builtin_amdgcn_mfma_f32_32x32x16_bf16(va1, pb, o1, 0, 0, 0);
        }
      }
      if (more) {
        *(bh8*)(&lds[nxt * 9216 + r8 * 72 + c8]) = rk;
        *(bh8*)(&lds[nxt * 9216 + 4608 + r8 * 72 + c8]) = rv;
      }
    }

    const float inv = 1.0f / lsum;
    __syncthreads();
    short* Ot = lds;
#pragma unroll
    for (int r = 0; r < 16; ++r) {
      const int d = (r & 3) + 8 * (r >> 2) + 4 * l5;
      Ot[(w * 32 + l31) * 72 + d]      = (short)f2bf(o0[r] * inv);
      Ot[(w * 32 + l31) * 72 + 32 + d] = (short)f2bf(o1[r] * inv);
    }
    __syncthreads();
    const int qrow = t >> 1, half = t & 1;
    short* orow = o + ((size_t)b * 2048 + qt * 256 + qrow) * 1024 + hh * 64 + half * 32;
#pragma unroll
    for (int i = 0; i < 4; ++i)
      *(bh8*)(orow + i * 8) = *(const bh8*)(&Ot[qrow * 72 + half * 32 + i * 8]);
  }
}

extern "C" void kernel_launch(void* const* d_in, const int* in_sizes, int n_in,
                              void* d_out, int out_size, void* d_ws, size_t ws_size,
                              hipStream_t stream) {
  const float* x   = (const float*)d_in[0];
  const float* Wq  = (const float*)d_in[1];
  const float* bq  = (const float*)d_in[2];
  const float* Wk  = (const float*)d_in[3];
  const float* bk  = (const float*)d_in[4];
  const float* Wv  = (const float*)d_in[5];
  const float* bv  = (const float*)d_in[6];
  const float* Wo  = (const float*)d_in[7];
  const float* bo  = (const float*)d_in[8];
  const float* W1  = (const float*)d_in[9];
  const float* bf1 = (const float*)d_in[10];
  const float* W2  = (const float*)d_in[11];
  const float* bf2 = (const float*)d_in[12];
  const float* g1  = (const float*)d_in[13];
  const float* be1 = (const float*)d_in[14];
  const float* g2  = (const float*)d_in[15];
  const float* be2 = (const float*)d_in[16];
  float* out = (float*)d_out;

  char* ws = (char*)d_ws;
  const size_t MB = 1u << 20;
  short* h_ob  = (short*)ws;                  // 16 MB: LN out; later attn out; later LN2 out
  short* qkv   = (short*)(ws + 16 * MB);      // 48 MB [8192][3072]
  short* f1    = (short*)(ws + 16 * MB);      // 64 MB alias (qkv+vt, dead at FF time)
  short* vtb   = (short*)(ws + 64 * MB);      // 16 MB [bh][64][2048]
  short* wqkvb = (short*)(ws + 80 * MB);      // 6 MB
  short* wob   = (short*)(ws + 86 * MB);      // 2 MB
  short* w1b   = (short*)(ws + 88 * MB);      // 8 MB
  short* w2b   = (short*)(ws + 96 * MB);      // 8 MB
  float* ct    = (float*)(ws + 104 * MB);     // 256 KB
  float* st    = ct + 65536;                  // 256 KB
  float* bqkv  = st + 65536;                  // 12 KB
  float* x2    = out;

  rope_table<<<256, 256, 0, stream>>>(ct, st);
  concat_bias<<<12, 256, 0, stream>>>(bq, bk, bv, bqkv);
  w2bf_all<<<dim3(4096, 6), 256, 0, stream>>>(Wq, Wk, Wv, Wo, W1, W2,
                                              wqkvb, wob, w1b, w2b);

  layernorm_bf<<<8192, 256, 0, stream>>>(x, g1, be1, h_ob);

  // QKV: M=8192 N=3072 K=1024, BM=128 -> grid 64*12 = 768 = 3 full waves
  gemm256<128, 0, 0, 1><<<768, 512, 0, stream>>>(h_ob, wqkvb, bqkv, nullptr, qkv, nullptr, 8192, 3072, 1024);

  rope_apply<<<dim3(4096, 2), 256, 0, stream>>>(qkv, ct, st);

  v_transpose<<<dim3(32, 64), 256, 0, stream>>>(qkv, vtb);

  flash_attn<<<256, 512, 0, stream>>>(qkv, vtb, h_ob);

  // Wo: M=8192 N=1024 K=1024, BM=128 -> grid 64*4 = 256, +res, fp32 out
  gemm256<128, 0, 1, 0><<<256, 512, 0, stream>>>(h_ob, wob, bo, x, nullptr, x2, 8192, 1024, 1024);

  layernorm_bf<<<8192, 256, 0, stream>>>(x2, g2, be2, h_ob);

  // FF1: M=8192 N=4096 K=1024, BM=256 -> grid 32*16 = 512 = 2 full waves, relu, bf16 out
  gemm256<256, 1, 0, 1><<<512, 512, 0, stream>>>(h_ob, w1b, bf1, nullptr, f1, nullptr, 8192, 4096, 1024);

  // FF2: M=8192 N=1024 K=4096, BM=128 -> grid 64*4 = 256, +res, fp32 out
  gemm256<128, 0, 1, 0><<<256, 512, 0, stream>>>(f1, w2b, bf2, x2, nullptr, out, 8192, 1024, 4096);
}